// Round 10
// baseline (162.951 us; speedup 1.0000x reference)
//
#include <hip/hip_runtime.h>

#define NFEAT 256
#define NHID  128

#define NBK   391     // node buckets of 256 nodes (ceil(100000/256))
#define EPB   4096    // edges per block in hist/scatter passes
#define NBLK  391     // edge blocks (ceil(1600000/4096))

typedef __bf16 bf16x8 __attribute__((ext_vector_type(8)));
typedef __bf16 bf16x4 __attribute__((ext_vector_type(4)));
typedef float  f32x4  __attribute__((ext_vector_type(4)));

// ---------------------------------------------------------------------------
// 1) Spectral norm: one power iteration -> scal[0] = 1/sigma
// ---------------------------------------------------------------------------
__global__ __launch_bounds__(256) void sigma_kernel(const float* __restrict__ W,
                                                    const float* __restrict__ u,
                                                    float* __restrict__ scal) {
    __shared__ float v[NHID];
    __shared__ float red[256];
    int tid = threadIdx.x;

    float t = 0.f;
    if (tid < NHID) {
        for (int i = 0; i < NFEAT; ++i) t += W[i * NHID + tid] * u[i];
    }
    red[tid] = (tid < NHID) ? t * t : 0.f;
    __syncthreads();
    for (int s = 128; s > 0; s >>= 1) {
        if (tid < s) red[tid] += red[tid + s];
        __syncthreads();
    }
    float nv = sqrtf(red[0]);
    float inv_nv = 1.f / (nv + 1e-12f);
    __syncthreads();
    if (tid < NHID) v[tid] = t * inv_nv;
    __syncthreads();

    float wv = 0.f;
    for (int j = 0; j < NHID; ++j) wv += W[tid * NHID + j] * v[j];
    red[tid] = wv * wv;
    __syncthreads();
    for (int s = 128; s > 0; s >>= 1) {
        if (tid < s) red[tid] += red[tid + s];
        __syncthreads();
    }
    if (tid == 0) {
        float n2  = red[0];
        float nwv = sqrtf(n2);
        float sigma = n2 / (nwv + 1e-12f);
        scal[0] = 1.f / sigma;
    }
}

// ---------------------------------------------------------------------------
// 2) W^T in bf16, scaled by 1/sigma
// ---------------------------------------------------------------------------
__global__ __launch_bounds__(256) void wt_kernel(const float* __restrict__ W,
                                                 const float* __restrict__ scal,
                                                 __bf16* __restrict__ WT) {
    int idx = blockIdx.x * 256 + threadIdx.x;
    int c = idx >> 8;
    int r = idx & 255;
    WT[c * NFEAT + r] = (__bf16)(W[r * NHID + c] * scal[0]);
}

// ---------------------------------------------------------------------------
// 3) C1: per-block histogram over coarse buckets (bucket = dst >> 8)
// ---------------------------------------------------------------------------
__global__ __launch_bounds__(256) void hist_kernel(const int* __restrict__ ecol,
                                                   int* __restrict__ blkhist, int E) {
    __shared__ int hist[NBK];
    int tid = threadIdx.x, b = blockIdx.x;
    for (int k = tid; k < NBK; k += 256) hist[k] = 0;
    __syncthreads();
    int e0 = b * EPB;
#pragma unroll
    for (int j = 0; j < 16; ++j) {
        int idx = e0 + j * 256 + tid;
        if (idx < E) atomicAdd(&hist[ecol[idx] >> 8], 1);
    }
    __syncthreads();
    for (int k = tid; k < NBK; k += 256) blkhist[k * NBLK + b] = hist[k];
}

// ---------------------------------------------------------------------------
// 4) C3a: exclusive scan of each blkhist row (one wave per bucket) + row total
// ---------------------------------------------------------------------------
__global__ __launch_bounds__(256) void scan_rows_kernel(int* __restrict__ blkhist,
                                                        int* __restrict__ btot) {
    int k = blockIdx.x * 4 + (threadIdx.x >> 6);
    int lane = threadIdx.x & 63;
    if (k >= NBK) return;
    int carry = 0;
    for (int c0 = 0; c0 < NBLK; c0 += 64) {
        int b = c0 + lane;
        int v = (b < NBLK) ? blkhist[k * NBLK + b] : 0;
        int orig = v;
#pragma unroll
        for (int d = 1; d < 64; d <<= 1) {
            int t = __shfl_up(v, (unsigned)d, 64);
            if (lane >= d) v += t;
        }
        if (b < NBLK) blkhist[k * NBLK + b] = carry + v - orig;   // exclusive
        carry += __shfl(v, 63, 64);
    }
    if (lane == 0) btot[k] = carry;
}

// ---------------------------------------------------------------------------
// 5) C3b: exclusive scan of bucket totals -> bucket_base[0..NBK]
// ---------------------------------------------------------------------------
__global__ __launch_bounds__(512) void scan_buckets_kernel(const int* __restrict__ btot,
                                                           int* __restrict__ bbase) {
    __shared__ int s[512];
    int tid = threadIdx.x;
    int v = (tid < NBK) ? btot[tid] : 0;
    s[tid] = v;
    __syncthreads();
    int val = v;
    for (int off = 1; off < 512; off <<= 1) {
        int t = (tid >= off) ? s[tid - off] : 0;
        __syncthreads();
        val += t;
        s[tid] = val;
        __syncthreads();
    }
    if (tid <= NBK) bbase[tid] = val - v;   // tid==NBK (v=0) -> total
}

// ---------------------------------------------------------------------------
// 6) C4: coarse scatter — LDS-reorder 4096 edges by bucket, write segments
// ---------------------------------------------------------------------------
__global__ __launch_bounds__(512) void coarse_scatter_kernel(const int* __restrict__ erow,
                                                             const int* __restrict__ ecol,
                                                             const int* __restrict__ blkhist,
                                                             const int* __restrict__ bbase,
                                                             unsigned int* __restrict__ rbuf,
                                                             int E) {
    __shared__ unsigned int rec[EPB];
    __shared__ unsigned short bk[EPB];
    __shared__ int hist[NBK], sc[512], lbase[NBK], lfill[NBK], gb[NBK];
    int tid = threadIdx.x, b = blockIdx.x;
    for (int k = tid; k < NBK; k += 512) { hist[k] = 0; lfill[k] = 0; }
    __syncthreads();
    int e0 = b * EPB;
    unsigned int rv[8];
    int kv[8];
#pragma unroll
    for (int j = 0; j < 8; ++j) {
        int idx = e0 + j * 512 + tid;
        if (idx < E) {
            int c = ecol[idx];
            int s = erow[idx];
            int k = c >> 8;
            kv[j] = k;
            rv[j] = ((unsigned int)(c & 255) << 24) | (unsigned int)s;
            atomicAdd(&hist[k], 1);
        } else kv[j] = -1;
    }
    __syncthreads();
    int hv = (tid < NBK) ? hist[tid] : 0;
    sc[tid] = hv;
    __syncthreads();
    int val = hv;
    for (int off = 1; off < 512; off <<= 1) {
        int t = (tid >= off) ? sc[tid - off] : 0;
        __syncthreads();
        val += t;
        sc[tid] = val;
        __syncthreads();
    }
    if (tid < NBK) {
        lbase[tid] = val - hv;
        gb[tid] = bbase[tid] + blkhist[tid * NBLK + b];
    }
    __syncthreads();
#pragma unroll
    for (int j = 0; j < 8; ++j) {
        if (kv[j] >= 0) {
            int p = lbase[kv[j]] + atomicAdd(&lfill[kv[j]], 1);
            rec[p] = rv[j];
            bk[p] = (unsigned short)kv[j];
        }
    }
    __syncthreads();
    int nval = E - e0;
    if (nval > EPB) nval = EPB;
    for (int p = tid; p < nval; p += 512) {
        int k = bk[p];
        rbuf[gb[k] + (p - lbase[k])] = rec[p];
    }
}

// ---------------------------------------------------------------------------
// 7) F: fine pass — one block per bucket: per-node CSR base, deg, dinv, ebuf.
// ---------------------------------------------------------------------------
__global__ __launch_bounds__(256) void fine_kernel(const unsigned int* __restrict__ rbuf,
                                                   const int* __restrict__ bbase,
                                                   int* __restrict__ base_g,
                                                   int* __restrict__ cnt_g,
                                                   float* __restrict__ dinv,
                                                   int* __restrict__ ebuf, int n) {
    __shared__ int cnt[256], lb[256], lf[256], sc[256];
    int tid = threadIdx.x, k = blockIdx.x;
    int seg0 = bbase[k], seg1 = bbase[k + 1];
    cnt[tid] = 0;
    lf[tid] = 0;
    __syncthreads();
    for (int j = seg0 + tid; j < seg1; j += 256)
        atomicAdd(&cnt[rbuf[j] >> 24], 1);
    __syncthreads();
    int cv = cnt[tid];
    sc[tid] = cv;
    __syncthreads();
    int val = cv;
    for (int off = 1; off < 256; off <<= 1) {
        int t = (tid >= off) ? sc[tid - off] : 0;
        __syncthreads();
        val += t;
        sc[tid] = val;
        __syncthreads();
    }
    lb[tid] = val - cv;   // exclusive
    __syncthreads();
    int node = k * 256 + tid;
    if (node < n) {
        base_g[node] = seg0 + lb[tid];
        cnt_g[node] = cv;
        dinv[node] = rsqrtf((float)cv + 1.f);
    }
    for (int j = seg0 + tid; j < seg1; j += 256) {
        unsigned int r = rbuf[j];
        int dl = r >> 24;
        int p = seg0 + lb[dl] + atomicAdd(&lf[dl], 1);
        ebuf[p] = (int)(r & 0xFFFFFFu);
    }
}

// ---------------------------------------------------------------------------
// 8) MFMA GEMM v6: LDS dbuf + REGISTER dbuf = load-to-use distance 2 chunks.
//    Loads for chunk c+2 issue at the TOP of iteration c (sched_barrier-pinned);
//    chunk c+1's regs (issued last iter, ~2 iters old) are cvt'd+ds_written at
//    the BOTTOM -> compiler emits counted vmcnt(4), never a full drain between
//    issue and use. Compute geometry/epilogue identical to R8/R9.
// ---------------------------------------------------------------------------
__device__ __forceinline__ void stage_tile(__bf16 (*buf)[64], const float4* pf,
                                           int srow, int sslot, int sr7) {
    float4 f0 = pf[0], f1 = pf[1], f2 = pf[2], f3 = pf[3];
    bf16x8 h0, h1;
    h0[0] = (__bf16)f0.x; h0[1] = (__bf16)f0.y; h0[2] = (__bf16)f0.z; h0[3] = (__bf16)f0.w;
    h0[4] = (__bf16)f1.x; h0[5] = (__bf16)f1.y; h0[6] = (__bf16)f1.z; h0[7] = (__bf16)f1.w;
    h1[0] = (__bf16)f2.x; h1[1] = (__bf16)f2.y; h1[2] = (__bf16)f2.z; h1[3] = (__bf16)f2.w;
    h1[4] = (__bf16)f3.x; h1[5] = (__bf16)f3.y; h1[6] = (__bf16)f3.z; h1[7] = (__bf16)f3.w;
    *(bf16x8*)&buf[srow][(sslot ^ sr7) * 8]       = h0;
    *(bf16x8*)&buf[srow][((sslot + 1) ^ sr7) * 8] = h1;
}

__device__ __forceinline__ void compute_chunk(const __bf16 (*buf)[64], const __bf16* wb,
                                              int crow0, int cr7, int kg, int c,
                                              f32x4* acc0, f32x4* acc1) {
#pragma unroll
    for (int ks = 0; ks < 2; ++ks) {
        int slog = ks * 4 + kg;
        bf16x8 af0 = *(const bf16x8*)&buf[crow0][(slog ^ cr7) * 8];
        bf16x8 af1 = *(const bf16x8*)&buf[crow0 + 16][(slog ^ cr7) * 8];
        int koff = c * 64 + ks * 32;
#pragma unroll
        for (int nt = 0; nt < 4; ++nt) {
            bf16x8 bf = *(const bf16x8*)(wb + (size_t)nt * 16 * NFEAT + koff);
            acc0[nt] = __builtin_amdgcn_mfma_f32_16x16x32_bf16(bf, af0, acc0[nt], 0, 0, 0);
            acc1[nt] = __builtin_amdgcn_mfma_f32_16x16x32_bf16(bf, af1, acc1[nt], 0, 0, 0);
        }
    }
}

__global__ __launch_bounds__(256, 4) void gemm_mfma_kernel(const float* __restrict__ x,
                                                           const __bf16* __restrict__ WT,
                                                           const float* __restrict__ dinv,
                                                           __bf16* __restrict__ xwb, int nn) {
    __shared__ __bf16 xs[2][64][64];   // 2 x 8KB

    int tid  = threadIdx.x;
    int lane = tid & 63;
    int w    = tid >> 6;                 // wave 0..3
    int rfrag = lane & 15;
    int kg    = lane >> 4;               // 0..3
    int row0 = blockIdx.x * 64;

    // ---- staging coords: thread t -> row t/4, 16-float segment t%4
    int srow = tid >> 2;                 // 0..63
    int sseg = tid & 3;                  // 0..3
    int gsrow = row0 + srow;
    if (gsrow >= nn) gsrow = nn - 1;
    const float4* sx = (const float4*)(x + (size_t)gsrow * NFEAT) + sseg * 4;
    int sslot = sseg * 2;                // logical 16B slot (0,2,4,6)
    int sr7 = srow & 7;

    // ---- compute coords
    int crow0 = (w & 1) * 32 + rfrag;
    int col0 = (w >> 1) * 64;
    int r0 = row0 + crow0;
    int r1 = r0 + 16;
    const __bf16* wb = WT + (size_t)(col0 + rfrag) * NFEAT + kg * 8;
    int cr7 = crow0 & 7;

    f32x4 acc0[4] = {};
    f32x4 acc1[4] = {};

    float4 pf0[4], pf1[4];   // reg staging: pf0 = even chunks, pf1 = odd chunks

    // ---- prologue: issue chunk0 -> pf0, chunk1 -> pf1; stage chunk0
    pf0[0] = sx[0];  pf0[1] = sx[1];  pf0[2] = sx[2];  pf0[3] = sx[3];
    pf1[0] = sx[16]; pf1[1] = sx[17]; pf1[2] = sx[18]; pf1[3] = sx[19];
    stage_tile(xs[0], pf0, srow, sslot, sr7);   // waits pf0 only (vmcnt(4))
    __syncthreads();

    // ---- iter 0: compute chunk0; issue chunk2 -> pf0; stage chunk1
    pf0[0] = sx[32]; pf0[1] = sx[33]; pf0[2] = sx[34]; pf0[3] = sx[35];
    __builtin_amdgcn_sched_barrier(0);          // pin: loads stay issued here
    compute_chunk(xs[0], wb, crow0, cr7, kg, 0, acc0, acc1);
    stage_tile(xs[1], pf1, srow, sslot, sr7);   // waits pf1 (vmcnt(4))
    __syncthreads();

    // ---- iter 1: compute chunk1; issue chunk3 -> pf1; stage chunk2
    pf1[0] = sx[48]; pf1[1] = sx[49]; pf1[2] = sx[50]; pf1[3] = sx[51];
    __builtin_amdgcn_sched_barrier(0);
    compute_chunk(xs[1], wb, crow0, cr7, kg, 1, acc0, acc1);
    stage_tile(xs[0], pf0, srow, sslot, sr7);   // chunk2, issued 2 iters ago
    __syncthreads();

    // ---- iter 2: compute chunk2; stage chunk3
    compute_chunk(xs[0], wb, crow0, cr7, kg, 2, acc0, acc1);
    stage_tile(xs[1], pf1, srow, sslot, sr7);   // chunk3, issued 2 iters ago
    __syncthreads();

    // ---- iter 3: compute chunk3
    compute_chunk(xs[1], wb, crow0, cr7, kg, 3, acc0, acc1);

    // ---- epilogue: lane owns rows r0/r1, cols col0 + nt*16 + kg*4 + reg
    if (r0 < nn) {
        float d = dinv[r0];
        __bf16* orow = xwb + (size_t)r0 * NHID + col0 + kg * 4;
#pragma unroll
        for (int nt = 0; nt < 4; ++nt) {
            bf16x4 v;
            v[0] = (__bf16)(acc0[nt][0] * d);
            v[1] = (__bf16)(acc0[nt][1] * d);
            v[2] = (__bf16)(acc0[nt][2] * d);
            v[3] = (__bf16)(acc0[nt][3] * d);
            *(bf16x4*)&orow[nt * 16] = v;
        }
    }
    if (r1 < nn) {
        float d = dinv[r1];
        __bf16* orow = xwb + (size_t)r1 * NHID + col0 + kg * 4;
#pragma unroll
        for (int nt = 0; nt < 4; ++nt) {
            bf16x4 v;
            v[0] = (__bf16)(acc1[nt][0] * d);
            v[1] = (__bf16)(acc1[nt][1] * d);
            v[2] = (__bf16)(acc1[nt][2] * d);
            v[3] = (__bf16)(acc1[nt][3] * d);
            *(bf16x4*)&orow[nt * 16] = v;
        }
    }
}

// ---------------------------------------------------------------------------
// 9) Gather + finalize: QUARTER-WAVE per node (16 lanes x 16B = 256B row).
// ---------------------------------------------------------------------------
__global__ __launch_bounds__(256) void gather_kernel(const uint4* __restrict__ xb4,
                                                     const int* __restrict__ base,
                                                     const int* __restrict__ cnt,
                                                     const int* __restrict__ ebuf,
                                                     const float* __restrict__ dinv,
                                                     const float* __restrict__ bias,
                                                     const float* __restrict__ pa,
                                                     float* __restrict__ out, int n) {
    int tid = threadIdx.x;
    int sub = tid & 15;                               // sublane in quarter-wave
    int node = (blockIdx.x * 256 + tid) >> 4;         // one node per 16 lanes
    if (node >= n) return;

    int b = base[node];
    int deg = cnt[node];

    uint4 s0 = xb4[(size_t)node * 16 + sub];
    float a0 = __uint_as_float(s0.x << 16);
    float a1 = __uint_as_float(s0.x & 0xffff0000u);
    float a2 = __uint_as_float(s0.y << 16);
    float a3 = __uint_as_float(s0.y & 0xffff0000u);
    float a4 = __uint_as_float(s0.z << 16);
    float a5 = __uint_as_float(s0.z & 0xffff0000u);
    float a6 = __uint_as_float(s0.w << 16);
    float a7 = __uint_as_float(s0.w & 0xffff0000u);

    int k = 0;
    for (; k + 4 <= deg; k += 4) {
        int r0 = ebuf[b + k + 0];
        int r1 = ebuf[b + k + 1];
        int r2 = ebuf[b + k + 2];
        int r3 = ebuf[b + k + 3];
        uint4 v0 = xb4[(size_t)r0 * 16 + sub];
        uint4 v1 = xb4[(size_t)r1 * 16 + sub];
        uint4 v2 = xb4[(size_t)r2 * 16 + sub];
        uint4 v3 = xb4[(size_t)r3 * 16 + sub];
        a0 += __uint_as_float(v0.x << 16) + __uint_as_float(v1.x << 16)
            + __uint_as_float(v2.x << 16) + __uint_as_float(v3.x << 16);
        a1 += __uint_as_float(v0.x & 0xffff0000u) + __uint_as_float(v1.x & 0xffff0000u)
            + __uint_as_float(v2.x & 0xffff0000u) + __uint_as_float(v3.x & 0xffff0000u);
        a2 += __uint_as_float(v0.y << 16) + __uint_as_float(v1.y << 16)
            + __uint_as_float(v2.y << 16) + __uint_as_float(v3.y << 16);
        a3 += __uint_as_float(v0.y & 0xffff0000u) + __uint_as_float(v1.y & 0xffff0000u)
            + __uint_as_float(v2.y & 0xffff0000u) + __uint_as_float(v3.y & 0xffff0000u);
        a4 += __uint_as_float(v0.z << 16) + __uint_as_float(v1.z << 16)
            + __uint_as_float(v2.z << 16) + __uint_as_float(v3.z << 16);
        a5 += __uint_as_float(v0.z & 0xffff0000u) + __uint_as_float(v1.z & 0xffff0000u)
            + __uint_as_float(v2.z & 0xffff0000u) + __uint_as_float(v3.z & 0xffff0000u);
        a6 += __uint_as_float(v0.w << 16) + __uint_as_float(v1.w << 16)
            + __uint_as_float(v2.w << 16) + __uint_as_float(v3.w << 16);
        a7 += __uint_as_float(v0.w & 0xffff0000u) + __uint_as_float(v1.w & 0xffff0000u)
            + __uint_as_float(v2.w & 0xffff0000u) + __uint_as_float(v3.w & 0xffff0000u);
    }
    for (; k < deg; ++k) {
        int r = ebuf[b + k];
        uint4 v = xb4[(size_t)r * 16 + sub];
        a0 += __uint_as_float(v.x << 16);
        a1 += __uint_as_float(v.x & 0xffff0000u);
        a2 += __uint_as_float(v.y << 16);
        a3 += __uint_as_float(v.y & 0xffff0000u);
        a4 += __uint_as_float(v.z << 16);
        a5 += __uint_as_float(v.z & 0xffff0000u);
        a6 += __uint_as_float(v.w << 16);
        a7 += __uint_as_float(v.w & 0xffff0000u);
    }

    float s = dinv[node];
    float alpha = pa[0];
    const float4* bb4 = (const float4*)bias;
    float4 b0 = bb4[sub * 2], b1 = bb4[sub * 2 + 1];
    float o0 = s * a0 + b0.x;
    float o1 = s * a1 + b0.y;
    float o2 = s * a2 + b0.z;
    float o3 = s * a3 + b0.w;
    float o4 = s * a4 + b1.x;
    float o5 = s * a5 + b1.y;
    float o6 = s * a6 + b1.z;
    float o7 = s * a7 + b1.w;
    o0 = o0 > 0.f ? o0 : alpha * o0;
    o1 = o1 > 0.f ? o1 : alpha * o1;
    o2 = o2 > 0.f ? o2 : alpha * o2;
    o3 = o3 > 0.f ? o3 : alpha * o3;
    o4 = o4 > 0.f ? o4 : alpha * o4;
    o5 = o5 > 0.f ? o5 : alpha * o5;
    o6 = o6 > 0.f ? o6 : alpha * o6;
    o7 = o7 > 0.f ? o7 : alpha * o7;
    float4* orow = (float4*)out + (size_t)node * 32 + sub * 2;
    orow[0] = make_float4(o0, o1, o2, o3);
    orow[1] = make_float4(o4, o5, o6, o7);
}

// ---------------------------------------------------------------------------
extern "C" void kernel_launch(void* const* d_in, const int* in_sizes, int n_in,
                              void* d_out, int out_size, void* d_ws, size_t ws_size,
                              hipStream_t stream) {
    const float* x    = (const float*)d_in[0];
    const int*   ei   = (const int*)d_in[1];   // int32, [2,E] row-major
    const float* W    = (const float*)d_in[2];
    const float* bias = (const float*)d_in[3];
    const float* pa   = (const float*)d_in[4];
    const float* u    = (const float*)d_in[5];

    int n = in_sizes[0] / NFEAT;     // 100000
    int e = in_sizes[1] / 2;         // 1600000
    const int* erow = ei;            // sources
    const int* ecol = ei + e;        // targets

    float* out = (float*)d_out;
    char* ws = (char*)d_ws;
    // workspace layout (bytes)
    float*        scal   = (float*)(ws);                    // 4 B
    int*          btot   = (int*)  (ws + 0x0001000);        // 392 ints
    int*          bbase  = (int*)  (ws + 0x0002000);        // 392 ints
    __bf16*       WT     = (__bf16*)(ws + 0x0010000);       // 64 KB
    int*          base_g = (int*)  (ws + 0x0100000);        // 400 KB
    int*          cnt_g  = (int*)  (ws + 0x0200000);        // 400 KB
    float*        dinv   = (float*)(ws + 0x0300000);        // 400 KB
    int*          blkhist= (int*)  (ws + 0x0400000);        // 611 KB
    unsigned int* rbuf   = (unsigned int*)(ws + 0x0500000); // 6.4 MB
    int*          ebuf   = (int*)  (ws + 0x0C00000);        // 6.4 MB
    __bf16*       xwb    = (__bf16*)(ws + 0x1300000);       // 25.6 MB

    sigma_kernel<<<1, 256, 0, stream>>>(W, u, scal);
    wt_kernel<<<(NFEAT * NHID) / 256, 256, 0, stream>>>(W, scal, WT);

    hist_kernel<<<NBLK, 256, 0, stream>>>(ecol, blkhist, e);
    scan_rows_kernel<<<(NBK + 3) / 4, 256, 0, stream>>>(blkhist, btot);
    scan_buckets_kernel<<<1, 512, 0, stream>>>(btot, bbase);
    coarse_scatter_kernel<<<NBLK, 512, 0, stream>>>(erow, ecol, blkhist, bbase, rbuf, e);
    fine_kernel<<<NBK, 256, 0, stream>>>(rbuf, bbase, base_g, cnt_g, dinv, ebuf, n);

    gemm_mfma_kernel<<<(n + 63) / 64, 256, 0, stream>>>(x, WT, dinv, xwb, n);

    long long gunits = (long long)n * 16;
    gather_kernel<<<(int)((gunits + 255) / 256), 256, 0, stream>>>(
        (const uint4*)xwb, base_g, cnt_g, ebuf, dinv, bias, pa, out, n);
}

// Round 11
// 157.339 us; speedup vs baseline: 1.0357x; 1.0357x over previous
//
#include <hip/hip_runtime.h>

#define NFEAT 256
#define NHID  128

#define NBK   391     // node buckets of 256 nodes (ceil(100000/256))
#define EPB   4096    // edges per block in hist/scatter passes
#define NBLK  391     // edge blocks (ceil(1600000/4096))

typedef __bf16 bf16x8 __attribute__((ext_vector_type(8)));
typedef __bf16 bf16x4 __attribute__((ext_vector_type(4)));
typedef float  f32x4  __attribute__((ext_vector_type(4)));

// ---------------------------------------------------------------------------
// 1) Spectral norm: one power iteration -> scal[0] = 1/sigma
// ---------------------------------------------------------------------------
__global__ __launch_bounds__(256) void sigma_kernel(const float* __restrict__ W,
                                                    const float* __restrict__ u,
                                                    float* __restrict__ scal) {
    __shared__ float v[NHID];
    __shared__ float red[256];
    int tid = threadIdx.x;

    float t = 0.f;
    if (tid < NHID) {
        for (int i = 0; i < NFEAT; ++i) t += W[i * NHID + tid] * u[i];
    }
    red[tid] = (tid < NHID) ? t * t : 0.f;
    __syncthreads();
    for (int s = 128; s > 0; s >>= 1) {
        if (tid < s) red[tid] += red[tid + s];
        __syncthreads();
    }
    float nv = sqrtf(red[0]);
    float inv_nv = 1.f / (nv + 1e-12f);
    __syncthreads();
    if (tid < NHID) v[tid] = t * inv_nv;
    __syncthreads();

    float wv = 0.f;
    for (int j = 0; j < NHID; ++j) wv += W[tid * NHID + j] * v[j];
    red[tid] = wv * wv;
    __syncthreads();
    for (int s = 128; s > 0; s >>= 1) {
        if (tid < s) red[tid] += red[tid + s];
        __syncthreads();
    }
    if (tid == 0) {
        float n2  = red[0];
        float nwv = sqrtf(n2);
        float sigma = n2 / (nwv + 1e-12f);
        scal[0] = 1.f / sigma;
    }
}

// ---------------------------------------------------------------------------
// 2) W^T in bf16, scaled by 1/sigma
// ---------------------------------------------------------------------------
__global__ __launch_bounds__(256) void wt_kernel(const float* __restrict__ W,
                                                 const float* __restrict__ scal,
                                                 __bf16* __restrict__ WT) {
    int idx = blockIdx.x * 256 + threadIdx.x;
    int c = idx >> 8;
    int r = idx & 255;
    WT[c * NFEAT + r] = (__bf16)(W[r * NHID + c] * scal[0]);
}

// ---------------------------------------------------------------------------
// 3) C1: per-block histogram over coarse buckets (bucket = dst >> 8)
// ---------------------------------------------------------------------------
__global__ __launch_bounds__(256) void hist_kernel(const int* __restrict__ ecol,
                                                   int* __restrict__ blkhist, int E) {
    __shared__ int hist[NBK];
    int tid = threadIdx.x, b = blockIdx.x;
    for (int k = tid; k < NBK; k += 256) hist[k] = 0;
    __syncthreads();
    int e0 = b * EPB;
#pragma unroll
    for (int j = 0; j < 16; ++j) {
        int idx = e0 + j * 256 + tid;
        if (idx < E) atomicAdd(&hist[ecol[idx] >> 8], 1);
    }
    __syncthreads();
    for (int k = tid; k < NBK; k += 256) blkhist[k * NBLK + b] = hist[k];
}

// ---------------------------------------------------------------------------
// 4) C3a: exclusive scan of each blkhist row (one wave per bucket) + row total
// ---------------------------------------------------------------------------
__global__ __launch_bounds__(256) void scan_rows_kernel(int* __restrict__ blkhist,
                                                        int* __restrict__ btot) {
    int k = blockIdx.x * 4 + (threadIdx.x >> 6);
    int lane = threadIdx.x & 63;
    if (k >= NBK) return;
    int carry = 0;
    for (int c0 = 0; c0 < NBLK; c0 += 64) {
        int b = c0 + lane;
        int v = (b < NBLK) ? blkhist[k * NBLK + b] : 0;
        int orig = v;
#pragma unroll
        for (int d = 1; d < 64; d <<= 1) {
            int t = __shfl_up(v, (unsigned)d, 64);
            if (lane >= d) v += t;
        }
        if (b < NBLK) blkhist[k * NBLK + b] = carry + v - orig;   // exclusive
        carry += __shfl(v, 63, 64);
    }
    if (lane == 0) btot[k] = carry;
}

// ---------------------------------------------------------------------------
// 5) C3b: exclusive scan of bucket totals -> bucket_base[0..NBK]
// ---------------------------------------------------------------------------
__global__ __launch_bounds__(512) void scan_buckets_kernel(const int* __restrict__ btot,
                                                           int* __restrict__ bbase) {
    __shared__ int s[512];
    int tid = threadIdx.x;
    int v = (tid < NBK) ? btot[tid] : 0;
    s[tid] = v;
    __syncthreads();
    int val = v;
    for (int off = 1; off < 512; off <<= 1) {
        int t = (tid >= off) ? s[tid - off] : 0;
        __syncthreads();
        val += t;
        s[tid] = val;
        __syncthreads();
    }
    if (tid <= NBK) bbase[tid] = val - v;   // tid==NBK (v=0) -> total
}

// ---------------------------------------------------------------------------
// 6) C4: coarse scatter — LDS-reorder 4096 edges by bucket, write segments
// ---------------------------------------------------------------------------
__global__ __launch_bounds__(512) void coarse_scatter_kernel(const int* __restrict__ erow,
                                                             const int* __restrict__ ecol,
                                                             const int* __restrict__ blkhist,
                                                             const int* __restrict__ bbase,
                                                             unsigned int* __restrict__ rbuf,
                                                             int E) {
    __shared__ unsigned int rec[EPB];
    __shared__ unsigned short bk[EPB];
    __shared__ int hist[NBK], sc[512], lbase[NBK], lfill[NBK], gb[NBK];
    int tid = threadIdx.x, b = blockIdx.x;
    for (int k = tid; k < NBK; k += 512) { hist[k] = 0; lfill[k] = 0; }
    __syncthreads();
    int e0 = b * EPB;
    unsigned int rv[8];
    int kv[8];
#pragma unroll
    for (int j = 0; j < 8; ++j) {
        int idx = e0 + j * 512 + tid;
        if (idx < E) {
            int c = ecol[idx];
            int s = erow[idx];
            int k = c >> 8;
            kv[j] = k;
            rv[j] = ((unsigned int)(c & 255) << 24) | (unsigned int)s;
            atomicAdd(&hist[k], 1);
        } else kv[j] = -1;
    }
    __syncthreads();
    int hv = (tid < NBK) ? hist[tid] : 0;
    sc[tid] = hv;
    __syncthreads();
    int val = hv;
    for (int off = 1; off < 512; off <<= 1) {
        int t = (tid >= off) ? sc[tid - off] : 0;
        __syncthreads();
        val += t;
        sc[tid] = val;
        __syncthreads();
    }
    if (tid < NBK) {
        lbase[tid] = val - hv;
        gb[tid] = bbase[tid] + blkhist[tid * NBLK + b];
    }
    __syncthreads();
#pragma unroll
    for (int j = 0; j < 8; ++j) {
        if (kv[j] >= 0) {
            int p = lbase[kv[j]] + atomicAdd(&lfill[kv[j]], 1);
            rec[p] = rv[j];
            bk[p] = (unsigned short)kv[j];
        }
    }
    __syncthreads();
    int nval = E - e0;
    if (nval > EPB) nval = EPB;
    for (int p = tid; p < nval; p += 512) {
        int k = bk[p];
        rbuf[gb[k] + (p - lbase[k])] = rec[p];
    }
}

// ---------------------------------------------------------------------------
// 7) F: fine pass — one block per bucket: per-node CSR base, deg, dinv, ebuf.
// ---------------------------------------------------------------------------
__global__ __launch_bounds__(256) void fine_kernel(const unsigned int* __restrict__ rbuf,
                                                   const int* __restrict__ bbase,
                                                   int* __restrict__ base_g,
                                                   int* __restrict__ cnt_g,
                                                   float* __restrict__ dinv,
                                                   int* __restrict__ ebuf, int n) {
    __shared__ int cnt[256], lb[256], lf[256], sc[256];
    int tid = threadIdx.x, k = blockIdx.x;
    int seg0 = bbase[k], seg1 = bbase[k + 1];
    cnt[tid] = 0;
    lf[tid] = 0;
    __syncthreads();
    for (int j = seg0 + tid; j < seg1; j += 256)
        atomicAdd(&cnt[rbuf[j] >> 24], 1);
    __syncthreads();
    int cv = cnt[tid];
    sc[tid] = cv;
    __syncthreads();
    int val = cv;
    for (int off = 1; off < 256; off <<= 1) {
        int t = (tid >= off) ? sc[tid - off] : 0;
        __syncthreads();
        val += t;
        sc[tid] = val;
        __syncthreads();
    }
    lb[tid] = val - cv;   // exclusive
    __syncthreads();
    int node = k * 256 + tid;
    if (node < n) {
        base_g[node] = seg0 + lb[tid];
        cnt_g[node] = cv;
        dinv[node] = rsqrtf((float)cv + 1.f);
    }
    for (int j = seg0 + tid; j < seg1; j += 256) {
        unsigned int r = rbuf[j];
        int dl = r >> 24;
        int p = seg0 + lb[dl] + atomicAdd(&lf[dl], 1);
        ebuf[p] = (int)(r & 0xFFFFFFu);
    }
}

// ---------------------------------------------------------------------------
// 8) MFMA GEMM v7: global_load_lds (width 16) staging of fp32 x-chunks,
//    raw s_barrier + counted vmcnt (catalog T3 minimum-2-phase):
//      iter c: B-loads(c) -> STAGE(c+1, DMA) -> compute(c) [compiler waits
//      B with vmcnt(4), STAGE stays in flight] -> vmcnt(0) -> s_barrier.
//    LDS dest is linear (DMA constraint); swizzle applied on the GLOBAL
//    source (slot ^ row&7) and on the ds_read side (rule #21 both-sides).
//    fp32 lands in LDS; cvt to bf16 at read time. Geometry/epilogue = R8.
// ---------------------------------------------------------------------------
__global__ __launch_bounds__(256) void gemm_mfma_kernel(const float* __restrict__ x,
                                                        const __bf16* __restrict__ WT,
                                                        const float* __restrict__ dinv,
                                                        __bf16* __restrict__ xwb, int nn) {
    __shared__ float xs[2][64][64];   // 2 x 16KB fp32 K-chunk tiles

    int tid  = threadIdx.x;
    int lane = tid & 63;
    int w    = tid >> 6;                 // wave 0..3
    int rfrag = lane & 15;
    int kg    = lane >> 4;               // 0..3
    int row0 = blockIdx.x * 64;

    int p16  = lane & 15;                // staging: 16B slot within row
    int rsub = lane >> 4;                // staging: row within 4-row group

    int crow0 = (w & 1) * 32 + rfrag;    // compute: chain0 row in tile
    int col0  = (w >> 1) * 64;           // 0 or 64
    int r0 = row0 + crow0;
    int r1 = r0 + 16;
    const __bf16* wb = WT + (size_t)(col0 + rfrag) * NFEAT + kg * 8;
    int cr7 = crow0 & 7;                 // same for crow0+16

    f32x4 acc0[4] = {};
    f32x4 acc1[4] = {};

    // DMA-stage chunk c into xs[buf]: 4 instrs/wave, each writes 4 rows x 256B.
    // Global source pre-swizzled: slot p16 at row r pulls logical slot p16^(r&7).
    auto STAGE = [&](int buf, int c) {
#pragma unroll
        for (int j = 0; j < 4; ++j) {
            int rloc = w * 16 + j * 4 + rsub;
            int grow = row0 + rloc;
            if (grow >= nn) grow = nn - 1;
            const float* src = x + (size_t)grow * NFEAT + c * 64 + ((p16 ^ (grow & 7)) << 2);
            __builtin_amdgcn_global_load_lds(
                (const __attribute__((address_space(1))) void*)src,
                (__attribute__((address_space(3))) void*)&xs[buf][w * 16 + j * 4][0],
                16, 0, 0);
        }
    };

    bf16x8 Bf[2][4];
    auto BLOAD = [&](int c) {
#pragma unroll
        for (int ks = 0; ks < 2; ++ks)
#pragma unroll
            for (int nt = 0; nt < 4; ++nt)
                Bf[ks][nt] = *(const bf16x8*)(wb + (size_t)nt * 16 * NFEAT + c * 64 + ks * 32);
    };

    auto MFMA_CHUNK = [&](int buf) {
#pragma unroll
        for (int ks = 0; ks < 2; ++ks) {
            int sA = kg * 2 + ks * 8;    // logical 16B slot of this fragment
            float4 a0lo = *(const float4*)&xs[buf][crow0][((sA) ^ cr7) * 4];
            float4 a0hi = *(const float4*)&xs[buf][crow0][((sA + 1) ^ cr7) * 4];
            float4 a1lo = *(const float4*)&xs[buf][crow0 + 16][((sA) ^ cr7) * 4];
            float4 a1hi = *(const float4*)&xs[buf][crow0 + 16][((sA + 1) ^ cr7) * 4];
            bf16x8 af0, af1;
            af0[0] = (__bf16)a0lo.x; af0[1] = (__bf16)a0lo.y;
            af0[2] = (__bf16)a0lo.z; af0[3] = (__bf16)a0lo.w;
            af0[4] = (__bf16)a0hi.x; af0[5] = (__bf16)a0hi.y;
            af0[6] = (__bf16)a0hi.z; af0[7] = (__bf16)a0hi.w;
            af1[0] = (__bf16)a1lo.x; af1[1] = (__bf16)a1lo.y;
            af1[2] = (__bf16)a1lo.z; af1[3] = (__bf16)a1lo.w;
            af1[4] = (__bf16)a1hi.x; af1[5] = (__bf16)a1hi.y;
            af1[6] = (__bf16)a1hi.z; af1[7] = (__bf16)a1hi.w;
#pragma unroll
            for (int nt = 0; nt < 4; ++nt) {
                acc0[nt] = __builtin_amdgcn_mfma_f32_16x16x32_bf16(Bf[ks][nt], af0, acc0[nt], 0, 0, 0);
                acc1[nt] = __builtin_amdgcn_mfma_f32_16x16x32_bf16(Bf[ks][nt], af1, acc1[nt], 0, 0, 0);
            }
        }
    };

#define DRAIN_BAR() do { \
        asm volatile("s_waitcnt vmcnt(0)" ::: "memory"); \
        __builtin_amdgcn_s_barrier(); } while (0)

    // ---- prologue: stage chunk 0
    STAGE(0, 0);
    DRAIN_BAR();

    // ---- iter 0: B(0); stage chunk1->buf1; compute buf0
    BLOAD(0);
    __builtin_amdgcn_sched_barrier(0);
    STAGE(1, 1);
    __builtin_amdgcn_sched_barrier(0);
    MFMA_CHUNK(0);
    DRAIN_BAR();

    // ---- iter 1: B(1); stage chunk2->buf0; compute buf1
    BLOAD(1);
    __builtin_amdgcn_sched_barrier(0);
    STAGE(0, 2);
    __builtin_amdgcn_sched_barrier(0);
    MFMA_CHUNK(1);
    DRAIN_BAR();

    // ---- iter 2: B(2); stage chunk3->buf1; compute buf0
    BLOAD(2);
    __builtin_amdgcn_sched_barrier(0);
    STAGE(1, 3);
    __builtin_amdgcn_sched_barrier(0);
    MFMA_CHUNK(0);
    DRAIN_BAR();

    // ---- iter 3: B(3); compute buf1
    BLOAD(3);
    MFMA_CHUNK(1);
#undef DRAIN_BAR

    // ---- epilogue: lane owns rows r0/r1, cols col0 + nt*16 + kg*4 + reg
    if (r0 < nn) {
        float d = dinv[r0];
        __bf16* orow = xwb + (size_t)r0 * NHID + col0 + kg * 4;
#pragma unroll
        for (int nt = 0; nt < 4; ++nt) {
            bf16x4 v;
            v[0] = (__bf16)(acc0[nt][0] * d);
            v[1] = (__bf16)(acc0[nt][1] * d);
            v[2] = (__bf16)(acc0[nt][2] * d);
            v[3] = (__bf16)(acc0[nt][3] * d);
            *(bf16x4*)&orow[nt * 16] = v;
        }
    }
    if (r1 < nn) {
        float d = dinv[r1];
        __bf16* orow = xwb + (size_t)r1 * NHID + col0 + kg * 4;
#pragma unroll
        for (int nt = 0; nt < 4; ++nt) {
            bf16x4 v;
            v[0] = (__bf16)(acc1[nt][0] * d);
            v[1] = (__bf16)(acc1[nt][1] * d);
            v[2] = (__bf16)(acc1[nt][2] * d);
            v[3] = (__bf16)(acc1[nt][3] * d);
            *(bf16x4*)&orow[nt * 16] = v;
        }
    }
}

// ---------------------------------------------------------------------------
// 9) Gather + finalize: QUARTER-WAVE per node (16 lanes x 16B = 256B row).
// ---------------------------------------------------------------------------
__global__ __launch_bounds__(256) void gather_kernel(const uint4* __restrict__ xb4,
                                                     const int* __restrict__ base,
                                                     const int* __restrict__ cnt,
                                                     const int* __restrict__ ebuf,
                                                     const float* __restrict__ dinv,
                                                     const float* __restrict__ bias,
                                                     const float* __restrict__ pa,
                                                     float* __restrict__ out, int n) {
    int tid = threadIdx.x;
    int sub = tid & 15;                               // sublane in quarter-wave
    int node = (blockIdx.x * 256 + tid) >> 4;         // one node per 16 lanes
    if (node >= n) return;

    int b = base[node];
    int deg = cnt[node];

    uint4 s0 = xb4[(size_t)node * 16 + sub];
    float a0 = __uint_as_float(s0.x << 16);
    float a1 = __uint_as_float(s0.x & 0xffff0000u);
    float a2 = __uint_as_float(s0.y << 16);
    float a3 = __uint_as_float(s0.y & 0xffff0000u);
    float a4 = __uint_as_float(s0.z << 16);
    float a5 = __uint_as_float(s0.z & 0xffff0000u);
    float a6 = __uint_as_float(s0.w << 16);
    float a7 = __uint_as_float(s0.w & 0xffff0000u);

    int k = 0;
    for (; k + 4 <= deg; k += 4) {
        int r0 = ebuf[b + k + 0];
        int r1 = ebuf[b + k + 1];
        int r2 = ebuf[b + k + 2];
        int r3 = ebuf[b + k + 3];
        uint4 v0 = xb4[(size_t)r0 * 16 + sub];
        uint4 v1 = xb4[(size_t)r1 * 16 + sub];
        uint4 v2 = xb4[(size_t)r2 * 16 + sub];
        uint4 v3 = xb4[(size_t)r3 * 16 + sub];
        a0 += __uint_as_float(v0.x << 16) + __uint_as_float(v1.x << 16)
            + __uint_as_float(v2.x << 16) + __uint_as_float(v3.x << 16);
        a1 += __uint_as_float(v0.x & 0xffff0000u) + __uint_as_float(v1.x & 0xffff0000u)
            + __uint_as_float(v2.x & 0xffff0000u) + __uint_as_float(v3.x & 0xffff0000u);
        a2 += __uint_as_float(v0.y << 16) + __uint_as_float(v1.y << 16)
            + __uint_as_float(v2.y << 16) + __uint_as_float(v3.y << 16);
        a3 += __uint_as_float(v0.y & 0xffff0000u) + __uint_as_float(v1.y & 0xffff0000u)
            + __uint_as_float(v2.y & 0xffff0000u) + __uint_as_float(v3.y & 0xffff0000u);
        a4 += __uint_as_float(v0.z << 16) + __uint_as_float(v1.z << 16)
            + __uint_as_float(v2.z << 16) + __uint_as_float(v3.z << 16);
        a5 += __uint_as_float(v0.z & 0xffff0000u) + __uint_as_float(v1.z & 0xffff0000u)
            + __uint_as_float(v2.z & 0xffff0000u) + __uint_as_float(v3.z & 0xffff0000u);
        a6 += __uint_as_float(v0.w << 16) + __uint_as_float(v1.w << 16)
            + __uint_as_float(v2.w << 16) + __uint_as_float(v3.w << 16);
        a7 += __uint_as_float(v0.w & 0xffff0000u) + __uint_as_float(v1.w & 0xffff0000u)
            + __uint_as_float(v2.w & 0xffff0000u) + __uint_as_float(v3.w & 0xffff0000u);
    }
    for (; k < deg; ++k) {
        int r = ebuf[b + k];
        uint4 v = xb4[(size_t)r * 16 + sub];
        a0 += __uint_as_float(v.x << 16);
        a1 += __uint_as_float(v.x & 0xffff0000u);
        a2 += __uint_as_float(v.y << 16);
        a3 += __uint_as_float(v.y & 0xffff0000u);
        a4 += __uint_as_float(v.z << 16);
        a5 += __uint_as_float(v.z & 0xffff0000u);
        a6 += __uint_as_float(v.w << 16);
        a7 += __uint_as_float(v.w & 0xffff0000u);
    }

    float s = dinv[node];
    float alpha = pa[0];
    const float4* bb4 = (const float4*)bias;
    float4 b0 = bb4[sub * 2], b1 = bb4[sub * 2 + 1];
    float o0 = s * a0 + b0.x;
    float o1 = s * a1 + b0.y;
    float o2 = s * a2 + b0.z;
    float o3 = s * a3 + b0.w;
    float o4 = s * a4 + b1.x;
    float o5 = s * a5 + b1.y;
    float o6 = s * a6 + b1.z;
    float o7 = s * a7 + b1.w;
    o0 = o0 > 0.f ? o0 : alpha * o0;
    o1 = o1 > 0.f ? o1 : alpha * o1;
    o2 = o2 > 0.f ? o2 : alpha * o2;
    o3 = o3 > 0.f ? o3 : alpha * o3;
    o4 = o4 > 0.f ? o4 : alpha * o4;
    o5 = o5 > 0.f ? o5 : alpha * o5;
    o6 = o6 > 0.f ? o6 : alpha * o6;
    o7 = o7 > 0.f ? o7 : alpha * o7;
    float4* orow = (float4*)out + (size_t)node * 32 + sub * 2;
    orow[0] = make_float4(o0, o1, o2, o3);
    orow[1] = make_float4(o4, o5, o6, o7);
}

// ---------------------------------------------------------------------------
extern "C" void kernel_launch(void* const* d_in, const int* in_sizes, int n_in,
                              void* d_out, int out_size, void* d_ws, size_t ws_size,
                              hipStream_t stream) {
    const float* x    = (const float*)d_in[0];
    const int*   ei   = (const int*)d_in[1];   // int32, [2,E] row-major
    const float* W    = (const float*)d_in[2];
    const float* bias = (const float*)d_in[3];
    const float* pa   = (const float*)d_in[4];
    const float* u    = (const float*)d_in[5];

    int n = in_sizes[0] / NFEAT;     // 100000
    int e = in_sizes[1] / 2;         // 1600000
    const int* erow = ei;            // sources
    const int* ecol = ei + e;        // targets

    float* out = (float*)d_out;
    char* ws = (char*)d_ws;
    // workspace layout (bytes)
    float*        scal   = (float*)(ws);                    // 4 B
    int*          btot   = (int*)  (ws + 0x0001000);        // 392 ints
    int*          bbase  = (int*)  (ws + 0x0002000);        // 392 ints
    __bf16*       WT     = (__bf16*)(ws + 0x0010000);       // 64 KB
    int*          base_g = (int*)  (ws + 0x0100000);        // 400 KB
    int*          cnt_g  = (int*)  (ws + 0x0200000);        // 400 KB
    float*        dinv   = (float*)(ws + 0x0300000);        // 400 KB
    int*          blkhist= (int*)  (ws + 0x0400000);        // 611 KB
    unsigned int* rbuf   = (unsigned int*)(ws + 0x0500000); // 6.4 MB
    int*          ebuf   = (int*)  (ws + 0x0C00000);        // 6.4 MB
    __bf16*       xwb    = (__bf16*)(ws + 0x1300000);       // 25.6 MB

    sigma_kernel<<<1, 256, 0, stream>>>(W, u, scal);
    wt_kernel<<<(NFEAT * NHID) / 256, 256, 0, stream>>>(W, scal, WT);

    hist_kernel<<<NBLK, 256, 0, stream>>>(ecol, blkhist, e);
    scan_rows_kernel<<<(NBK + 3) / 4, 256, 0, stream>>>(blkhist, btot);
    scan_buckets_kernel<<<1, 512, 0, stream>>>(btot, bbase);
    coarse_scatter_kernel<<<NBLK, 512, 0, stream>>>(erow, ecol, blkhist, bbase, rbuf, e);
    fine_kernel<<<NBK, 256, 0, stream>>>(rbuf, bbase, base_g, cnt_g, dinv, ebuf, n);

    gemm_mfma_kernel<<<(n + 63) / 64, 256, 0, stream>>>(x, WT, dinv, xwb, n);

    long long gunits = (long long)n * 16;
    gather_kernel<<<(int)((gunits + 255) / 256), 256, 0, stream>>>(
        (const uint4*)xwb, base_g, cnt_g, ebuf, dinv, bias, pa, out, n);
}

// Round 12
// 146.114 us; speedup vs baseline: 1.1152x; 1.0768x over previous
//
#include <hip/hip_runtime.h>

#define NFEAT 256
#define NHID  128

#define NBK   391     // node buckets of 256 nodes (ceil(100000/256))
#define EPB   4096    // edges per block in the coarse pass
#define NBLK  391     // edge blocks (ceil(1600000/4096))
#define SEGW  4608    // fixed bucket segment stride (mean 4092 + 8 sigma)

typedef __bf16 bf16x8 __attribute__((ext_vector_type(8)));
typedef __bf16 bf16x4 __attribute__((ext_vector_type(4)));
typedef float  f32x4  __attribute__((ext_vector_type(4)));

// ---------------------------------------------------------------------------
// 1) Spectral norm (one power iteration) -> scal[0] = 1/sigma.
//    Also zeroes the global bucket_fill counters (free ride, 1 block).
// ---------------------------------------------------------------------------
__global__ __launch_bounds__(256) void sigma_kernel(const float* __restrict__ W,
                                                    const float* __restrict__ u,
                                                    float* __restrict__ scal,
                                                    int* __restrict__ bucket_fill) {
    __shared__ float v[NHID];
    __shared__ float red[256];
    int tid = threadIdx.x;

    if (tid < NBK) bucket_fill[tid] = 0;
    if (tid + 256 < NBK) bucket_fill[tid + 256] = 0;

    float t = 0.f;
    if (tid < NHID) {
        for (int i = 0; i < NFEAT; ++i) t += W[i * NHID + tid] * u[i];
    }
    red[tid] = (tid < NHID) ? t * t : 0.f;
    __syncthreads();
    for (int s = 128; s > 0; s >>= 1) {
        if (tid < s) red[tid] += red[tid + s];
        __syncthreads();
    }
    float nv = sqrtf(red[0]);
    float inv_nv = 1.f / (nv + 1e-12f);
    __syncthreads();
    if (tid < NHID) v[tid] = t * inv_nv;
    __syncthreads();

    float wv = 0.f;
    for (int j = 0; j < NHID; ++j) wv += W[tid * NHID + j] * v[j];
    red[tid] = wv * wv;
    __syncthreads();
    for (int s = 128; s > 0; s >>= 1) {
        if (tid < s) red[tid] += red[tid + s];
        __syncthreads();
    }
    if (tid == 0) {
        float n2  = red[0];
        float nwv = sqrtf(n2);
        float sigma = n2 / (nwv + 1e-12f);
        scal[0] = 1.f / sigma;
    }
}

// ---------------------------------------------------------------------------
// 2) W^T in bf16, scaled by 1/sigma
// ---------------------------------------------------------------------------
__global__ __launch_bounds__(256) void wt_kernel(const float* __restrict__ W,
                                                 const float* __restrict__ scal,
                                                 __bf16* __restrict__ WT) {
    int idx = blockIdx.x * 256 + threadIdx.x;
    int c = idx >> 8;
    int r = idx & 255;
    WT[c * NFEAT + r] = (__bf16)(W[r * NHID + c] * scal[0]);
}

// ---------------------------------------------------------------------------
// 3) FUSED kernel: blocks [0, ngemm) run the MFMA GEMM (v7 structure, no
//    dinv — moved to gather); blocks [ngemm, ngemm+NBLK) run the coarse
//    edge-bucketing pass with fixed-stride segments (no hist/scan kernels).
//    Both paths share one 32KB LDS buffer (union).
// ---------------------------------------------------------------------------
__global__ __launch_bounds__(256) void fused_kernel(const float* __restrict__ x,
                                                    const __bf16* __restrict__ WT,
                                                    __bf16* __restrict__ xwb,
                                                    const int* __restrict__ erow,
                                                    const int* __restrict__ ecol,
                                                    int* __restrict__ bucket_fill,
                                                    unsigned int* __restrict__ rbuf,
                                                    int nn, int E, int ngemm) {
    __shared__ __attribute__((aligned(16))) char sbuf[32768];

    int tid  = threadIdx.x;

    if ((int)blockIdx.x < ngemm) {
        // =================== GEMM path (R11 v7, dinv removed) ===============
        float (*xs)[64][64] = (float (*)[64][64])sbuf;   // 2 x 16KB fp32 tiles

        int lane = tid & 63;
        int w    = tid >> 6;                 // wave 0..3
        int rfrag = lane & 15;
        int kg    = lane >> 4;               // 0..3
        int row0 = blockIdx.x * 64;

        int p16  = lane & 15;                // staging: 16B slot within row
        int rsub = lane >> 4;                // staging: row within 4-row group

        int crow0 = (w & 1) * 32 + rfrag;
        int col0  = (w >> 1) * 64;
        int r0 = row0 + crow0;
        int r1 = r0 + 16;
        const __bf16* wb = WT + (size_t)(col0 + rfrag) * NFEAT + kg * 8;
        int cr7 = crow0 & 7;

        f32x4 acc0[4] = {};
        f32x4 acc1[4] = {};

        auto STAGE = [&](int buf, int c) {
#pragma unroll
            for (int j = 0; j < 4; ++j) {
                int rloc = w * 16 + j * 4 + rsub;
                int grow = row0 + rloc;
                if (grow >= nn) grow = nn - 1;
                const float* src = x + (size_t)grow * NFEAT + c * 64 + ((p16 ^ (grow & 7)) << 2);
                __builtin_amdgcn_global_load_lds(
                    (const __attribute__((address_space(1))) void*)src,
                    (__attribute__((address_space(3))) void*)&xs[buf][w * 16 + j * 4][0],
                    16, 0, 0);
            }
        };

        bf16x8 Bf[2][4];
        auto BLOAD = [&](int c) {
#pragma unroll
            for (int ks = 0; ks < 2; ++ks)
#pragma unroll
                for (int nt = 0; nt < 4; ++nt)
                    Bf[ks][nt] = *(const bf16x8*)(wb + (size_t)nt * 16 * NFEAT + c * 64 + ks * 32);
        };

        auto MFMA_CHUNK = [&](int buf) {
#pragma unroll
            for (int ks = 0; ks < 2; ++ks) {
                int sA = kg * 2 + ks * 8;
                float4 a0lo = *(const float4*)&xs[buf][crow0][((sA) ^ cr7) * 4];
                float4 a0hi = *(const float4*)&xs[buf][crow0][((sA + 1) ^ cr7) * 4];
                float4 a1lo = *(const float4*)&xs[buf][crow0 + 16][((sA) ^ cr7) * 4];
                float4 a1hi = *(const float4*)&xs[buf][crow0 + 16][((sA + 1) ^ cr7) * 4];
                bf16x8 af0, af1;
                af0[0] = (__bf16)a0lo.x; af0[1] = (__bf16)a0lo.y;
                af0[2] = (__bf16)a0lo.z; af0[3] = (__bf16)a0lo.w;
                af0[4] = (__bf16)a0hi.x; af0[5] = (__bf16)a0hi.y;
                af0[6] = (__bf16)a0hi.z; af0[7] = (__bf16)a0hi.w;
                af1[0] = (__bf16)a1lo.x; af1[1] = (__bf16)a1lo.y;
                af1[2] = (__bf16)a1lo.z; af1[3] = (__bf16)a1lo.w;
                af1[4] = (__bf16)a1hi.x; af1[5] = (__bf16)a1hi.y;
                af1[6] = (__bf16)a1hi.z; af1[7] = (__bf16)a1hi.w;
#pragma unroll
                for (int nt = 0; nt < 4; ++nt) {
                    acc0[nt] = __builtin_amdgcn_mfma_f32_16x16x32_bf16(Bf[ks][nt], af0, acc0[nt], 0, 0, 0);
                    acc1[nt] = __builtin_amdgcn_mfma_f32_16x16x32_bf16(Bf[ks][nt], af1, acc1[nt], 0, 0, 0);
                }
            }
        };

#define DRAIN_BAR() do { \
            asm volatile("s_waitcnt vmcnt(0)" ::: "memory"); \
            __builtin_amdgcn_s_barrier(); } while (0)

        STAGE(0, 0);
        DRAIN_BAR();

        BLOAD(0);
        __builtin_amdgcn_sched_barrier(0);
        STAGE(1, 1);
        __builtin_amdgcn_sched_barrier(0);
        MFMA_CHUNK(0);
        DRAIN_BAR();

        BLOAD(1);
        __builtin_amdgcn_sched_barrier(0);
        STAGE(0, 2);
        __builtin_amdgcn_sched_barrier(0);
        MFMA_CHUNK(1);
        DRAIN_BAR();

        BLOAD(2);
        __builtin_amdgcn_sched_barrier(0);
        STAGE(1, 3);
        __builtin_amdgcn_sched_barrier(0);
        MFMA_CHUNK(0);
        DRAIN_BAR();

        BLOAD(3);
        MFMA_CHUNK(1);
#undef DRAIN_BAR

        if (r0 < nn) {
            __bf16* orow = xwb + (size_t)r0 * NHID + col0 + kg * 4;
#pragma unroll
            for (int nt = 0; nt < 4; ++nt) {
                bf16x4 v;
                v[0] = (__bf16)acc0[nt][0];
                v[1] = (__bf16)acc0[nt][1];
                v[2] = (__bf16)acc0[nt][2];
                v[3] = (__bf16)acc0[nt][3];
                *(bf16x4*)&orow[nt * 16] = v;
            }
        }
        if (r1 < nn) {
            __bf16* orow = xwb + (size_t)r1 * NHID + col0 + kg * 4;
#pragma unroll
            for (int nt = 0; nt < 4; ++nt) {
                bf16x4 v;
                v[0] = (__bf16)acc1[nt][0];
                v[1] = (__bf16)acc1[nt][1];
                v[2] = (__bf16)acc1[nt][2];
                v[3] = (__bf16)acc1[nt][3];
                *(bf16x4*)&orow[nt * 16] = v;
            }
        }
        return;
    }

    // =================== COARSE path (fixed-stride segments) ===============
    unsigned int*   rec   = (unsigned int*)sbuf;               // 16384 B
    unsigned short* bkk   = (unsigned short*)(sbuf + 16384);   //  8192 B
    int*            hist  = (int*)(sbuf + 24576);              //  1564 B
    int*            lbase = (int*)(sbuf + 24576 + 1564);
    int*            lfill = (int*)(sbuf + 24576 + 3128);
    int*            gb    = (int*)(sbuf + 24576 + 4692);       // ends 30832

    int b = blockIdx.x - ngemm;
    for (int k = tid; k < NBK; k += 256) { hist[k] = 0; lfill[k] = 0; }
    __syncthreads();

    int e0 = b * EPB;
    unsigned int rv[16];
    int kv[16];
#pragma unroll
    for (int j = 0; j < 16; ++j) {
        int idx = e0 + j * 256 + tid;
        if (idx < E) {
            int c = ecol[idx];
            int s = erow[idx];
            int k = c >> 8;
            kv[j] = k;
            rv[j] = ((unsigned int)(c & 255) << 24) | (unsigned int)s;
            atomicAdd(&hist[k], 1);
        } else kv[j] = -1;
    }
    __syncthreads();

    // wave-0 shuffle scan of hist[0..390] -> lbase (exclusive)
    if (tid < 64) {
        int carry = 0;
        for (int c0 = 0; c0 < NBK; c0 += 64) {
            int i = c0 + tid;
            int vv = (i < NBK) ? hist[i] : 0;
            int orig = vv;
#pragma unroll
            for (int d = 1; d < 64; d <<= 1) {
                int t = __shfl_up(vv, (unsigned)d, 64);
                if (tid >= d) vv += t;
            }
            if (i < NBK) lbase[i] = carry + vv - orig;
            carry += __shfl(vv, 63, 64);
        }
    }
    __syncthreads();

    // reserve global span per bucket: gb[k] = k*SEGW + fetch_add(fill[k], hist[k])
    if (tid < NBK) gb[tid] = tid * SEGW + atomicAdd(&bucket_fill[tid], hist[tid]);
    if (tid + 256 < NBK) gb[tid + 256] = (tid + 256) * SEGW
                                       + atomicAdd(&bucket_fill[tid + 256], hist[tid + 256]);
    __syncthreads();

#pragma unroll
    for (int j = 0; j < 16; ++j) {
        if (kv[j] >= 0) {
            int p = lbase[kv[j]] + atomicAdd(&lfill[kv[j]], 1);
            rec[p] = rv[j];
            bkk[p] = (unsigned short)kv[j];
        }
    }
    __syncthreads();

    int nval = E - e0;
    if (nval > EPB) nval = EPB;
    for (int p = tid; p < nval; p += 256) {
        int k = bkk[p];
        rbuf[gb[k] + (p - lbase[k])] = rec[p];
    }
}

// ---------------------------------------------------------------------------
// 4) F: fine pass — one block per bucket: per-node CSR base, deg, dinv, ebuf.
//    Segments at fixed offsets k*SEGW, counts from bucket_fill.
// ---------------------------------------------------------------------------
__global__ __launch_bounds__(256) void fine_kernel(const unsigned int* __restrict__ rbuf,
                                                   const int* __restrict__ bucket_fill,
                                                   int* __restrict__ base_g,
                                                   int* __restrict__ cnt_g,
                                                   float* __restrict__ dinv,
                                                   int* __restrict__ ebuf, int n) {
    __shared__ int cnt[256], lb[256], lf[256], sc[256];
    int tid = threadIdx.x, k = blockIdx.x;
    int seg0 = k * SEGW, seg1 = seg0 + bucket_fill[k];
    cnt[tid] = 0;
    lf[tid] = 0;
    __syncthreads();
    for (int j = seg0 + tid; j < seg1; j += 256)
        atomicAdd(&cnt[rbuf[j] >> 24], 1);
    __syncthreads();
    int cv = cnt[tid];
    sc[tid] = cv;
    __syncthreads();
    int val = cv;
    for (int off = 1; off < 256; off <<= 1) {
        int t = (tid >= off) ? sc[tid - off] : 0;
        __syncthreads();
        val += t;
        sc[tid] = val;
        __syncthreads();
    }
    lb[tid] = val - cv;   // exclusive
    __syncthreads();
    int node = k * 256 + tid;
    if (node < n) {
        base_g[node] = seg0 + lb[tid];
        cnt_g[node] = cv;
        dinv[node] = rsqrtf((float)cv + 1.f);
    }
    for (int j = seg0 + tid; j < seg1; j += 256) {
        unsigned int r = rbuf[j];
        int dl = r >> 24;
        int p = seg0 + lb[dl] + atomicAdd(&lf[dl], 1);
        ebuf[p] = (int)(r & 0xFFFFFFu);
    }
}

// ---------------------------------------------------------------------------
// 5) Gather + finalize: QUARTER-WAVE per node (16 lanes x 16B = 256B row).
//    xwb now holds (x.W/sigma) WITHOUT dinv; per-edge dinv[src] applied via fma.
//    out = dinv[n]*( dinv[n]*xw[n] + sum dinv[r]*xw[r] ) + bias, then PReLU.
// ---------------------------------------------------------------------------
__global__ __launch_bounds__(256) void gather_kernel(const uint4* __restrict__ xb4,
                                                     const int* __restrict__ base,
                                                     const int* __restrict__ cnt,
                                                     const int* __restrict__ ebuf,
                                                     const float* __restrict__ dinv,
                                                     const float* __restrict__ bias,
                                                     const float* __restrict__ pa,
                                                     float* __restrict__ out, int n) {
    int tid = threadIdx.x;
    int sub = tid & 15;                               // sublane in quarter-wave
    int node = (blockIdx.x * 256 + tid) >> 4;         // one node per 16 lanes
    if (node >= n) return;

    int b = base[node];
    int deg = cnt[node];
    float dn = dinv[node];

    uint4 s0 = xb4[(size_t)node * 16 + sub];
    float a0 = dn * __uint_as_float(s0.x << 16);
    float a1 = dn * __uint_as_float(s0.x & 0xffff0000u);
    float a2 = dn * __uint_as_float(s0.y << 16);
    float a3 = dn * __uint_as_float(s0.y & 0xffff0000u);
    float a4 = dn * __uint_as_float(s0.z << 16);
    float a5 = dn * __uint_as_float(s0.z & 0xffff0000u);
    float a6 = dn * __uint_as_float(s0.w << 16);
    float a7 = dn * __uint_as_float(s0.w & 0xffff0000u);

    int k = 0;
    for (; k + 4 <= deg; k += 4) {
        int r0 = ebuf[b + k + 0];
        int r1 = ebuf[b + k + 1];
        int r2 = ebuf[b + k + 2];
        int r3 = ebuf[b + k + 3];
        float d0 = dinv[r0], d1 = dinv[r1], d2 = dinv[r2], d3 = dinv[r3];
        uint4 v0 = xb4[(size_t)r0 * 16 + sub];
        uint4 v1 = xb4[(size_t)r1 * 16 + sub];
        uint4 v2 = xb4[(size_t)r2 * 16 + sub];
        uint4 v3 = xb4[(size_t)r3 * 16 + sub];
        a0 += d0 * __uint_as_float(v0.x << 16) + d1 * __uint_as_float(v1.x << 16)
            + d2 * __uint_as_float(v2.x << 16) + d3 * __uint_as_float(v3.x << 16);
        a1 += d0 * __uint_as_float(v0.x & 0xffff0000u) + d1 * __uint_as_float(v1.x & 0xffff0000u)
            + d2 * __uint_as_float(v2.x & 0xffff0000u) + d3 * __uint_as_float(v3.x & 0xffff0000u);
        a2 += d0 * __uint_as_float(v0.y << 16) + d1 * __uint_as_float(v1.y << 16)
            + d2 * __uint_as_float(v2.y << 16) + d3 * __uint_as_float(v3.y << 16);
        a3 += d0 * __uint_as_float(v0.y & 0xffff0000u) + d1 * __uint_as_float(v1.y & 0xffff0000u)
            + d2 * __uint_as_float(v2.y & 0xffff0000u) + d3 * __uint_as_float(v3.y & 0xffff0000u);
        a4 += d0 * __uint_as_float(v0.z << 16) + d1 * __uint_as_float(v1.z << 16)
            + d2 * __uint_as_float(v2.z << 16) + d3 * __uint_as_float(v3.z << 16);
        a5 += d0 * __uint_as_float(v0.z & 0xffff0000u) + d1 * __uint_as_float(v1.z & 0xffff0000u)
            + d2 * __uint_as_float(v2.z & 0xffff0000u) + d3 * __uint_as_float(v3.z & 0xffff0000u);
        a6 += d0 * __uint_as_float(v0.w << 16) + d1 * __uint_as_float(v1.w << 16)
            + d2 * __uint_as_float(v2.w << 16) + d3 * __uint_as_float(v3.w << 16);
        a7 += d0 * __uint_as_float(v0.w & 0xffff0000u) + d1 * __uint_as_float(v1.w & 0xffff0000u)
            + d2 * __uint_as_float(v2.w & 0xffff0000u) + d3 * __uint_as_float(v3.w & 0xffff0000u);
    }
    for (; k < deg; ++k) {
        int r = ebuf[b + k];
        float d = dinv[r];
        uint4 v = xb4[(size_t)r * 16 + sub];
        a0 += d * __uint_as_float(v.x << 16);
        a1 += d * __uint_as_float(v.x & 0xffff0000u);
        a2 += d * __uint_as_float(v.y << 16);
        a3 += d * __uint_as_float(v.y & 0xffff0000u);
        a4 += d * __uint_as_float(v.z << 16);
        a5 += d * __uint_as_float(v.z & 0xffff0000u);
        a6 += d * __uint_as_float(v.w << 16);
        a7 += d * __uint_as_float(v.w & 0xffff0000u);
    }

    float alpha = pa[0];
    const float4* bb4 = (const float4*)bias;
    float4 b0 = bb4[sub * 2], b1 = bb4[sub * 2 + 1];
    float o0 = dn * a0 + b0.x;
    float o1 = dn * a1 + b0.y;
    float o2 = dn * a2 + b0.z;
    float o3 = dn * a3 + b0.w;
    float o4 = dn * a4 + b1.x;
    float o5 = dn * a5 + b1.y;
    float o6 = dn * a6 + b1.z;
    float o7 = dn * a7 + b1.w;
    o0 = o0 > 0.f ? o0 : alpha * o0;
    o1 = o1 > 0.f ? o1 : alpha * o1;
    o2 = o2 > 0.f ? o2 : alpha * o2;
    o3 = o3 > 0.f ? o3 : alpha * o3;
    o4 = o4 > 0.f ? o4 : alpha * o4;
    o5 = o5 > 0.f ? o5 : alpha * o5;
    o6 = o6 > 0.f ? o6 : alpha * o6;
    o7 = o7 > 0.f ? o7 : alpha * o7;
    float4* orow = (float4*)out + (size_t)node * 32 + sub * 2;
    orow[0] = make_float4(o0, o1, o2, o3);
    orow[1] = make_float4(o4, o5, o6, o7);
}

// ---------------------------------------------------------------------------
extern "C" void kernel_launch(void* const* d_in, const int* in_sizes, int n_in,
                              void* d_out, int out_size, void* d_ws, size_t ws_size,
                              hipStream_t stream) {
    const float* x    = (const float*)d_in[0];
    const int*   ei   = (const int*)d_in[1];   // int32, [2,E] row-major
    const float* W    = (const float*)d_in[2];
    const float* bias = (const float*)d_in[3];
    const float* pa   = (const float*)d_in[4];
    const float* u    = (const float*)d_in[5];

    int n = in_sizes[0] / NFEAT;     // 100000
    int e = in_sizes[1] / 2;         // 1600000
    const int* erow = ei;            // sources
    const int* ecol = ei + e;        // targets

    float* out = (float*)d_out;
    char* ws = (char*)d_ws;
    // workspace layout (bytes)
    float*        scal   = (float*)(ws);                    // 4 B
    int*          bfill  = (int*)  (ws + 0x0002000);        // 391 ints
    __bf16*       WT     = (__bf16*)(ws + 0x0010000);       // 64 KB
    int*          base_g = (int*)  (ws + 0x0100000);        // 400 KB
    int*          cnt_g  = (int*)  (ws + 0x0200000);        // 400 KB
    float*        dinv   = (float*)(ws + 0x0300000);        // 400 KB
    unsigned int* rbuf   = (unsigned int*)(ws + 0x0500000); // 6.9 MB (391*4608*4)
    int*          ebuf   = (int*)  (ws + 0x0C00000);        // 6.9 MB
    __bf16*       xwb    = (__bf16*)(ws + 0x1300000);       // 25.6 MB

    int ngemm = (n + 63) / 64;       // 1563

    sigma_kernel<<<1, 256, 0, stream>>>(W, u, scal, bfill);
    wt_kernel<<<(NFEAT * NHID) / 256, 256, 0, stream>>>(W, scal, WT);

    fused_kernel<<<ngemm + NBLK, 256, 0, stream>>>(x, WT, xwb, erow, ecol,
                                                   bfill, rbuf, n, e, ngemm);

    fine_kernel<<<NBK, 256, 0, stream>>>(rbuf, bfill, base_g, cnt_g, dinv, ebuf, n);

    long long gunits = (long long)n * 16;
    gather_kernel<<<(int)((gunits + 255) / 256), 256, 0, stream>>>(
        (const uint4*)xwb, base_g, cnt_g, ebuf, dinv, bias, pa, out, n);
}